// Round 1
// baseline (17498.186 us; speedup 1.0000x reference)
//
#include <hip/hip_runtime.h>
#include <math.h>

#define HID 256
#define NCLASS 5
#define DEPTH 11
#define NB 128           // batch
#define NN 2047          // nodes
#define RPB 8            // tree-rows per block

__device__ __forceinline__ float dot4(float4 w, float4 v, float acc) {
    acc = fmaf(w.x, v.x, acc);
    acc = fmaf(w.y, v.y, acc);
    acc = fmaf(w.z, v.z, acc);
    acc = fmaf(w.w, v.w, acc);
    return acc;
}

__device__ __forceinline__ float sigmoidf_(float x) {
    return 1.0f / (1.0f + __expf(-x));
}

template<bool LEAF>
__global__ __launch_bounds__(256)
void tree_level_kernel(
    const float* __restrict__ x,
    const float* __restrict__ W_i, const float* __restrict__ U_i, const float* __restrict__ b_i,
    const float* __restrict__ W_f, const float* __restrict__ U_f, const float* __restrict__ b_f,
    const float* __restrict__ W_o, const float* __restrict__ U_o, const float* __restrict__ b_o,
    const float* __restrict__ W_u, const float* __restrict__ U_u, const float* __restrict__ b_u,
    const float* __restrict__ W_s, const float* __restrict__ b_s,
    const float* __restrict__ h_child, const float* __restrict__ c_child,  // (B, 2M, HID)
    float* __restrict__ h_out, float* __restrict__ c_out,                  // (B, M, HID)
    float* __restrict__ out,                                               // (B, NN, NCLASS)
    int s, int lgM)
{
    __shared__ float xs[RPB][HID];
    __shared__ float hLs[RPB][HID];
    __shared__ float hRs[RPB][HID];

    const int t = threadIdx.x;
    const int M = 1 << lgM;
    const int row0 = blockIdx.x * RPB;

    // ---- stage this block's rows into LDS (coalesced) ----
    #pragma unroll
    for (int r = 0; r < RPB; ++r) {
        int row = row0 + r;
        int b = row >> lgM;
        int m = row & (M - 1);
        xs[r][t] = x[((size_t)b * NN + s + m) * HID + t];
        if (!LEAF) {
            const float* hrow = h_child + ((size_t)b * (M << 1) + (m << 1)) * HID;
            hLs[r][t] = hrow[t];
            hRs[r][t] = hrow[HID + t];
        }
    }
    __syncthreads();

    // ---- accumulators: thread t owns output channel t for all RPB rows ----
    float acc_i[RPB], acc_o[RPB], acc_u[RPB], acc_wf[RPB], acc_f0[RPB], acc_f1[RPB];
    #pragma unroll
    for (int r = 0; r < RPB; ++r) {
        acc_i[r]  = b_i[t];
        acc_o[r]  = b_o[t];
        acc_u[r]  = b_u[t];
        acc_wf[r] = b_f[t];
        acc_f0[r] = 0.f;
        acc_f1[r] = 0.f;
    }

    const int K4 = HID / 4;
    const float4* wi4  = ((const float4*)W_i) + (size_t)t * K4;
    const float4* wo4  = ((const float4*)W_o) + (size_t)t * K4;
    const float4* wu4  = ((const float4*)W_u) + (size_t)t * K4;
    const float4* wf4  = ((const float4*)W_f) + (size_t)t * K4;
    const float4* ui0  = ((const float4*)U_i) + (size_t)t * K4;
    const float4* ui1  = ui0  + (size_t)HID * K4;
    const float4* uo0  = ((const float4*)U_o) + (size_t)t * K4;
    const float4* uo1  = uo0  + (size_t)HID * K4;
    const float4* uu0  = ((const float4*)U_u) + (size_t)t * K4;
    const float4* uu1  = uu0  + (size_t)HID * K4;
    const float4* uf00 = ((const float4*)U_f) + (size_t)t * K4;
    const float4* uf01 = uf00 + (size_t)HID * K4;
    const float4* uf10 = uf01 + (size_t)HID * K4;
    const float4* uf11 = uf10 + (size_t)HID * K4;

    // ---- main K loop: weights from L2 (float4 streams), rows broadcast from LDS ----
    for (int kk = 0; kk < K4; ++kk) {
        // x-side gates (always)
        {
            float4 wi = wi4[kk], wo = wo4[kk], wu = wu4[kk], wf = wf4[kk];
            #pragma unroll
            for (int r = 0; r < RPB; ++r) {
                float4 xv = ((const float4*)xs[r])[kk];
                acc_i[r]  = dot4(wi, xv, acc_i[r]);
                acc_o[r]  = dot4(wo, xv, acc_o[r]);
                acc_u[r]  = dot4(wu, xv, acc_u[r]);
                acc_wf[r] = dot4(wf, xv, acc_wf[r]);
            }
        }
        if (!LEAF) {
            // left-child gates
            {
                float4 vi = ui0[kk], vo = uo0[kk], vu = uu0[kk], vf0 = uf00[kk], vf1 = uf10[kk];
                #pragma unroll
                for (int r = 0; r < RPB; ++r) {
                    float4 hv = ((const float4*)hLs[r])[kk];
                    acc_i[r]  = dot4(vi,  hv, acc_i[r]);
                    acc_o[r]  = dot4(vo,  hv, acc_o[r]);
                    acc_u[r]  = dot4(vu,  hv, acc_u[r]);
                    acc_f0[r] = dot4(vf0, hv, acc_f0[r]);
                    acc_f1[r] = dot4(vf1, hv, acc_f1[r]);
                }
            }
            // right-child gates
            {
                float4 vi = ui1[kk], vo = uo1[kk], vu = uu1[kk], vf0 = uf01[kk], vf1 = uf11[kk];
                #pragma unroll
                for (int r = 0; r < RPB; ++r) {
                    float4 hv = ((const float4*)hRs[r])[kk];
                    acc_i[r]  = dot4(vi,  hv, acc_i[r]);
                    acc_o[r]  = dot4(vo,  hv, acc_o[r]);
                    acc_u[r]  = dot4(vu,  hv, acc_u[r]);
                    acc_f0[r] = dot4(vf0, hv, acc_f0[r]);
                    acc_f1[r] = dot4(vf1, hv, acc_f1[r]);
                }
            }
        }
    }

    // ---- elementwise epilogue: gates -> c,h; write level buffers ----
    float hreg[RPB];
    #pragma unroll
    for (int r = 0; r < RPB; ++r) {
        int row = row0 + r;
        int b = row >> lgM;
        int m = row & (M - 1);
        float ig = sigmoidf_(acc_i[r]);
        float og = sigmoidf_(acc_o[r]);
        float ug = tanhf(acc_u[r]);
        float c;
        if (LEAF) {
            c = ig * ug;  // children are zero
        } else {
            float f0 = sigmoidf_(acc_wf[r] + acc_f0[r]);
            float f1 = sigmoidf_(acc_wf[r] + acc_f1[r]);
            const float* crow = c_child + ((size_t)b * (M << 1) + (m << 1)) * HID;
            c = fmaf(f0, crow[t], fmaf(f1, crow[HID + t], ig * ug));
        }
        float h = og * tanhf(c);
        size_t o = ((size_t)b * M + m) * HID + t;
        h_out[o] = h;
        c_out[o] = c;
        hreg[r] = h;
    }

    // ---- logits + softmax (reuse xs to hold h) ----
    __syncthreads();   // all k-loop LDS reads done before overwrite
    #pragma unroll
    for (int r = 0; r < RPB; ++r) xs[r][t] = hreg[r];
    __syncthreads();

    const int wv = t >> 6;
    const int lane = t & 63;
    for (int r = wv; r < RPB; r += 4) {
        float p0 = 0.f, p1 = 0.f, p2 = 0.f, p3 = 0.f, p4 = 0.f;
        for (int k = lane; k < HID; k += 64) {
            float hv = xs[r][k];
            p0 = fmaf(W_s[0 * HID + k], hv, p0);
            p1 = fmaf(W_s[1 * HID + k], hv, p1);
            p2 = fmaf(W_s[2 * HID + k], hv, p2);
            p3 = fmaf(W_s[3 * HID + k], hv, p3);
            p4 = fmaf(W_s[4 * HID + k], hv, p4);
        }
        #pragma unroll
        for (int off = 32; off; off >>= 1) {
            p0 += __shfl_down(p0, off);
            p1 += __shfl_down(p1, off);
            p2 += __shfl_down(p2, off);
            p3 += __shfl_down(p3, off);
            p4 += __shfl_down(p4, off);
        }
        if (lane == 0) {
            float l0 = p0 + b_s[0], l1 = p1 + b_s[1], l2 = p2 + b_s[2];
            float l3 = p3 + b_s[3], l4 = p4 + b_s[4];
            float mx = fmaxf(fmaxf(fmaxf(l0, l1), fmaxf(l2, l3)), l4);
            float e0 = __expf(l0 - mx), e1 = __expf(l1 - mx), e2 = __expf(l2 - mx);
            float e3 = __expf(l3 - mx), e4 = __expf(l4 - mx);
            float inv = 1.0f / (e0 + e1 + e2 + e3 + e4);
            int row = row0 + r;
            int b = row >> lgM;
            int m = row & (M - 1);
            float* orow = out + ((size_t)b * NN + s + m) * NCLASS;
            orow[0] = e0 * inv;
            orow[1] = e1 * inv;
            orow[2] = e2 * inv;
            orow[3] = e3 * inv;
            orow[4] = e4 * inv;
        }
    }
}

extern "C" void kernel_launch(void* const* d_in, const int* in_sizes, int n_in,
                              void* d_out, int out_size, void* d_ws, size_t ws_size,
                              hipStream_t stream) {
    const float* x   = (const float*)d_in[0];
    const float* W_i = (const float*)d_in[1];
    const float* U_i = (const float*)d_in[2];
    const float* b_i = (const float*)d_in[3];
    const float* W_f = (const float*)d_in[4];
    const float* U_f = (const float*)d_in[5];
    const float* b_f = (const float*)d_in[6];
    const float* W_o = (const float*)d_in[7];
    const float* U_o = (const float*)d_in[8];
    const float* b_o = (const float*)d_in[9];
    const float* W_u = (const float*)d_in[10];
    const float* U_u = (const float*)d_in[11];
    const float* b_u = (const float*)d_in[12];
    const float* W_s = (const float*)d_in[13];
    const float* b_s = (const float*)d_in[14];
    float* out = (float*)d_out;
    float* ws  = (float*)d_ws;

    // ping buffer holds even-distance levels (leaf level 10: 1024 nodes),
    // pong holds odd-distance levels (max 512 nodes).
    const size_t L = (size_t)NB * 1024 * HID;   // 33,554,432 floats
    float* ping_h = ws;
    float* ping_c = ping_h + L;
    float* pong_h = ping_c + L;
    float* pong_c = pong_h + L / 2;
    // total ws use: 3.0L floats = 402,653,184 bytes

    for (int lvl = DEPTH - 1; lvl >= 0; --lvl) {
        const int M = 1 << lvl;
        const int s = M - 1;
        const int grid = (NB * M) / RPB;
        const bool toPing = (((DEPTH - 1 - lvl) & 1) == 0);
        float* ho = toPing ? ping_h : pong_h;
        float* co = toPing ? ping_c : pong_c;
        const float* hc = toPing ? pong_h : ping_h;
        const float* cc = toPing ? pong_c : ping_c;

        if (lvl == DEPTH - 1) {
            tree_level_kernel<true><<<grid, 256, 0, stream>>>(
                x, W_i, U_i, b_i, W_f, U_f, b_f, W_o, U_o, b_o, W_u, U_u, b_u,
                W_s, b_s, nullptr, nullptr, ho, co, out, s, lvl);
        } else {
            tree_level_kernel<false><<<grid, 256, 0, stream>>>(
                x, W_i, U_i, b_i, W_f, U_f, b_f, W_o, U_o, b_o, W_u, U_u, b_u,
                W_s, b_s, hc, cc, ho, co, out, s, lvl);
        }
    }
}

// Round 2
// 2064.488 us; speedup vs baseline: 8.4758x; 8.4758x over previous
//
#include <hip/hip_runtime.h>
#include <math.h>

#define HID 256
#define NCLASS 5
#define DEPTH 11
#define NB 128
#define NN 2047

typedef __attribute__((ext_vector_type(8))) short bf16x8_t;
typedef __attribute__((ext_vector_type(4))) float f32x4_t;

__device__ __forceinline__ float bf2f(unsigned short u) {
    return __uint_as_float(((unsigned)u) << 16);
}
__device__ __forceinline__ unsigned short f2bf(float f) {
    unsigned x = __float_as_uint(f);
    unsigned r = (x + 0x7fff + ((x >> 16) & 1)) >> 16;   // RNE
    return (unsigned short)r;
}
__device__ __forceinline__ float sigmoidf_(float x) {
    return 1.0f / (1.0f + __expf(-x));
}

// ---------------- weight concat/cast: Wcat (1280 n, 768 k) bf16, B^T layout ----------------
// n = chblk*320 + g*64 + c64 ; gate g: 0=i,1=o,2=u,3=f0,4=f1
// k: [0,256)=W_g , [256,512)=U left , [512,768)=U right
__global__ __launch_bounds__(256)
void prep_wcat(const float* __restrict__ W_i, const float* __restrict__ U_i,
               const float* __restrict__ W_f, const float* __restrict__ U_f,
               const float* __restrict__ W_o, const float* __restrict__ U_o,
               const float* __restrict__ W_u, const float* __restrict__ U_u,
               unsigned short* __restrict__ Wcat)
{
    int idx = blockIdx.x * 256 + threadIdx.x;     // 0 .. 1280*768-1
    int k = idx % 768;
    int n = idx / 768;
    int chblk = n / 320;
    int r = n % 320;
    int g = r >> 6;
    int ch = chblk * 64 + (r & 63);
    int seg = k >> 8;
    int kk = k & 255;
    float v;
    if (seg == 0) {
        const float* W = (g == 0) ? W_i : (g == 1) ? W_o : (g == 2) ? W_u : W_f;
        v = W[ch * 256 + kk];
    } else {
        int side = seg - 1;
        if (g == 0)      v = U_i[(side * 256 + ch) * 256 + kk];
        else if (g == 1) v = U_o[(side * 256 + ch) * 256 + kk];
        else if (g == 2) v = U_u[(side * 256 + ch) * 256 + kk];
        else {
            int fg = g - 3;
            v = U_f[((fg * 2 + side) * 256 + ch) * 256 + kk];
        }
    }
    Wcat[(size_t)n * 768 + k] = f2bf(v);
}

// ---------------- x cast fp32 -> bf16 ----------------
__global__ __launch_bounds__(256)
void cast_x_kernel(const float* __restrict__ x, unsigned short* __restrict__ xb)
{
    size_t i = ((size_t)blockIdx.x * 256 + threadIdx.x) * 8;
    float4 a = *(const float4*)(x + i);
    float4 b = *(const float4*)(x + i + 4);
    unsigned short o[8] = {f2bf(a.x), f2bf(a.y), f2bf(a.z), f2bf(a.w),
                           f2bf(b.x), f2bf(b.y), f2bf(b.z), f2bf(b.w)};
    *(uint4*)(xb + i) = *(uint4*)o;
}

// ---------------- fused level GEMM + LSTM epilogue ----------------
// Block: 256 thr = 4 waves. Tile: 64 rows x (NT*16) cols. 16x16x32 bf16 MFMA.
// LDS frag-granule layout with XOR swizzle: granule(tile t, kq, quad, low4) at
//   ((kq*TILES + t)*64 + quad*16 + (low4 ^ (kq*4+quad))) * 16 bytes.
template<bool LEAF>
__global__ __launch_bounds__(256)
void level_gemm(const unsigned short* __restrict__ xb,
                const unsigned short* __restrict__ hA,       // (rows,512) [hL|hR]; null if LEAF
                const unsigned short* __restrict__ Wcat,
                const float* __restrict__ c_child,           // (child rows,256); null if LEAF
                const float* __restrict__ b_i, const float* __restrict__ b_o,
                const float* __restrict__ b_u, const float* __restrict__ b_f,
                float* __restrict__ c_out,                   // (rows,256)
                unsigned short* __restrict__ hA_parent,      // (rows/2,512) or null (lvl 0)
                unsigned short* __restrict__ h_all,          // (B,NN,256)
                int lgM)
{
    constexpr int NT  = LEAF ? 12 : 20;     // n-tiles (16 wide): leaf = i,o,u only
    constexpr int NK  = LEAF ? 4  : 12;     // k64 steps (K=256 / 768)
    constexpr int NPW = NT / 2;             // n-tiles per wave
    constexpr int BOFF = 8192;              // A region bytes
    constexpr int SMEM = BOFF + NT * 2048;  // + B region

    __shared__ __align__(16) char smem[SMEM];

    const int tid  = threadIdx.x;
    const int wave = tid >> 6, lane = tid & 63;
    const int quad = lane >> 4, l15 = lane & 15;
    const int R0    = blockIdx.x * 64;
    const int chblk = blockIdx.y;
    const int nbase = chblk * 320;
    const int M = 1 << lgM, s = M - 1;
    const int mt0 = (wave & 1) * 2;
    const int nt0 = (wave >> 1) * NPW;

    f32x4_t acc[2][NPW];
    #pragma unroll
    for (int mi = 0; mi < 2; ++mi)
        #pragma unroll
        for (int j = 0; j < NPW; ++j)
            acc[mi][j] = (f32x4_t){0.f, 0.f, 0.f, 0.f};

    for (int step = 0; step < NK; ++step) {
        const int k0 = step * 64;
        __syncthreads();
        // ---- stage A: 64 rows x 64 k  (512 granules, 2 per thread) ----
        #pragma unroll
        for (int it = 0; it < 2; ++it) {
            int gran = tid + it * 256;
            int r = gran >> 3, g = gran & 7;
            const unsigned short* src;
            if (LEAF || k0 < 256) {
                int grow = R0 + r;
                int b = grow >> lgM, m = grow & (M - 1);
                src = xb + ((size_t)b * NN + s + m) * 256 + (k0 + g * 8);
            } else {
                src = hA + (size_t)(R0 + r) * 512 + (k0 - 256 + g * 8);
            }
            uint4 v = *(const uint4*)src;
            int kq = g >> 2, qd = g & 3;
            int dst = ((kq * 4 + (r >> 4)) * 64 + qd * 16 + ((r & 15) ^ g)) * 16;
            *(uint4*)(smem + dst) = v;
        }
        // ---- stage B: NT*16 rows x 64 k ----
        #pragma unroll
        for (int it = 0; it < NT / 2; ++it) {
            int gran = tid + it * 256;
            int n = gran >> 3, g = gran & 7;
            const unsigned short* src = Wcat + (size_t)(nbase + n) * 768 + (k0 + g * 8);
            uint4 v = *(const uint4*)src;
            int kq = g >> 2, qd = g & 3;
            int dst = BOFF + ((kq * NT + (n >> 4)) * 64 + qd * 16 + ((n & 15) ^ g)) * 16;
            *(uint4*)(smem + dst) = v;
        }
        __syncthreads();
        // ---- compute: 2 kq x (2 m-tiles x NPW n-tiles) per wave ----
        #pragma unroll
        for (int kq = 0; kq < 2; ++kq) {
            const int g = kq * 4 + quad;
            bf16x8_t af[2];
            #pragma unroll
            for (int mi = 0; mi < 2; ++mi) {
                int addr = ((kq * 4 + (mt0 + mi)) * 64 + quad * 16 + (l15 ^ g)) * 16;
                af[mi] = *(const bf16x8_t*)(smem + addr);
            }
            #pragma unroll
            for (int j = 0; j < NPW; ++j) {
                int baddr = BOFF + ((kq * NT + nt0 + j) * 64 + quad * 16 + (l15 ^ g)) * 16;
                bf16x8_t bfr = *(const bf16x8_t*)(smem + baddr);
                acc[0][j] = __builtin_amdgcn_mfma_f32_16x16x32_bf16(af[0], bfr, acc[0][j], 0, 0, 0);
                acc[1][j] = __builtin_amdgcn_mfma_f32_16x16x32_bf16(af[1], bfr, acc[1][j], 0, 0, 0);
            }
        }
    }

    // ---- epilogue: two 32-row halves through LDS fp32 scratch ----
    constexpr int ESTRIDE = NT * 16 + 1;
    float* LDSf = (float*)smem;

    for (int half = 0; half < 2; ++half) {
        __syncthreads();
        if ((wave & 1) == half) {
            #pragma unroll
            for (int mi = 0; mi < 2; ++mi)
                #pragma unroll
                for (int j = 0; j < NPW; ++j)
                    #pragma unroll
                    for (int reg = 0; reg < 4; ++reg) {
                        int lrow = mi * 16 + quad * 4 + reg;
                        int col = (nt0 + j) * 16 + l15;
                        LDSf[lrow * ESTRIDE + col] = acc[mi][j][reg];
                    }
        }
        __syncthreads();

        int rl = tid >> 3;            // 0..31
        int c0 = (tid & 7) * 8;       // 8 channels per thread
        int grow = R0 + half * 32 + rl;
        int b = grow >> lgM, m = grow & (M - 1);
        int gch0 = chblk * 64 + c0;

        float cv[8];
        unsigned short hv[8];
        const float* crow = LEAF ? nullptr
                                 : c_child + ((size_t)b * (M << 1) + (m << 1)) * 256;
        #pragma unroll
        for (int q = 0; q < 8; ++q) {
            int cc = c0 + q;
            int gch = gch0 + q;
            float pi = LDSf[rl * ESTRIDE + cc]        + b_i[gch];
            float po = LDSf[rl * ESTRIDE + 64 + cc]   + b_o[gch];
            float pu = LDSf[rl * ESTRIDE + 128 + cc]  + b_u[gch];
            float ig = sigmoidf_(pi);
            float og = sigmoidf_(po);
            float ug = tanhf(pu);
            float c;
            if (LEAF) {
                c = ig * ug;
            } else {
                float pf0 = LDSf[rl * ESTRIDE + 192 + cc] + b_f[gch];
                float pf1 = LDSf[rl * ESTRIDE + 256 + cc] + b_f[gch];
                float f0 = sigmoidf_(pf0);
                float f1 = sigmoidf_(pf1);
                c = fmaf(f0, crow[gch], fmaf(f1, crow[256 + gch], ig * ug));
            }
            float h = og * tanhf(c);
            cv[q] = c;
            hv[q] = f2bf(h);
        }
        // vector stores
        float* cdst = c_out + (size_t)grow * 256 + gch0;
        *(float4*)(cdst)     = *(float4*)(cv);
        *(float4*)(cdst + 4) = *(float4*)(cv + 4);
        unsigned short* hdst = h_all + ((size_t)b * NN + s + m) * 256 + gch0;
        *(uint4*)hdst = *(uint4*)hv;
        if (hA_parent) {
            unsigned short* pdst = hA_parent + ((size_t)b * (M >> 1) + (m >> 1)) * 512
                                   + (m & 1) * 256 + gch0;
            *(uint4*)pdst = *(uint4*)hv;
        }
    }
}

// ---------------- classifier softmax over all nodes ----------------
__global__ __launch_bounds__(256)
void softmax_kernel(const unsigned short* __restrict__ h_all,
                    const float* __restrict__ W_s, const float* __restrict__ b_s,
                    float* __restrict__ out)
{
    __shared__ float Ws[5 * 256];
    int tid = threadIdx.x;
    for (int i = tid; i < 1280; i += 256) Ws[i] = W_s[i];
    __syncthreads();

    int r = tid >> 3, q = tid & 7;
    size_t row = (size_t)blockIdx.x * 32 + r;       // row in [0, 128*2047)
    const unsigned short* hp = h_all + row * 256 + q * 32;

    float p0 = 0.f, p1 = 0.f, p2 = 0.f, p3 = 0.f, p4 = 0.f;
    #pragma unroll
    for (int kk = 0; kk < 32; kk += 8) {
        uint4 raw = *(const uint4*)(hp + kk);
        unsigned short hu[8];
        *(uint4*)hu = raw;
        #pragma unroll
        for (int e = 0; e < 8; ++e) {
            float hvv = bf2f(hu[e]);
            int k = q * 32 + kk + e;
            p0 = fmaf(Ws[k],        hvv, p0);
            p1 = fmaf(Ws[256 + k],  hvv, p1);
            p2 = fmaf(Ws[512 + k],  hvv, p2);
            p3 = fmaf(Ws[768 + k],  hvv, p3);
            p4 = fmaf(Ws[1024 + k], hvv, p4);
        }
    }
    #pragma unroll
    for (int off = 4; off; off >>= 1) {
        p0 += __shfl_down(p0, off, 8);
        p1 += __shfl_down(p1, off, 8);
        p2 += __shfl_down(p2, off, 8);
        p3 += __shfl_down(p3, off, 8);
        p4 += __shfl_down(p4, off, 8);
    }
    if (q == 0) {
        float l0 = p0 + b_s[0], l1 = p1 + b_s[1], l2 = p2 + b_s[2];
        float l3 = p3 + b_s[3], l4 = p4 + b_s[4];
        float mx = fmaxf(fmaxf(fmaxf(l0, l1), fmaxf(l2, l3)), l4);
        float e0 = __expf(l0 - mx), e1 = __expf(l1 - mx), e2 = __expf(l2 - mx);
        float e3 = __expf(l3 - mx), e4 = __expf(l4 - mx);
        float inv = 1.0f / (e0 + e1 + e2 + e3 + e4);
        float* orow = out + row * NCLASS;
        orow[0] = e0 * inv;
        orow[1] = e1 * inv;
        orow[2] = e2 * inv;
        orow[3] = e3 * inv;
        orow[4] = e4 * inv;
    }
}

extern "C" void kernel_launch(void* const* d_in, const int* in_sizes, int n_in,
                              void* d_out, int out_size, void* d_ws, size_t ws_size,
                              hipStream_t stream) {
    const float* x   = (const float*)d_in[0];
    const float* W_i = (const float*)d_in[1];
    const float* U_i = (const float*)d_in[2];
    const float* b_i = (const float*)d_in[3];
    const float* W_f = (const float*)d_in[4];
    const float* U_f = (const float*)d_in[5];
    const float* b_f = (const float*)d_in[6];
    const float* W_o = (const float*)d_in[7];
    const float* U_o = (const float*)d_in[8];
    const float* b_o = (const float*)d_in[9];
    const float* W_u = (const float*)d_in[10];
    const float* U_u = (const float*)d_in[11];
    const float* b_u = (const float*)d_in[12];
    const float* W_s = (const float*)d_in[13];
    const float* b_s = (const float*)d_in[14];
    float* out = (float*)d_out;

    // workspace layout (bytes):
    char* p = (char*)d_ws;
    unsigned short* Wcat  = (unsigned short*)p; p += 2097152;       // 1280*768*2 rounded
    unsigned short* xb    = (unsigned short*)p; p += 134152192;     // 128*2047*256*2
    unsigned short* h_all = (unsigned short*)p; p += 134152192;
    unsigned short* hA0   = (unsigned short*)p; p += 33554432;      // even levels (max lvl8: 32768 rows * 1KB)
    unsigned short* hA1   = (unsigned short*)p; p += 67108864;      // odd levels (lvl9: 65536 rows * 1KB)
    float* cb0 = (float*)p; p += 134217728;                         // even levels (lvl10: 131072 rows * 1KB)
    float* cb1 = (float*)p; p += 67108864;                          // odd levels
    // total: ~572.4 MB

    prep_wcat<<<3840, 256, 0, stream>>>(W_i, U_i, W_f, U_f, W_o, U_o, W_u, U_u, Wcat);
    cast_x_kernel<<<32752, 256, 0, stream>>>(x, xb);

    for (int lvl = DEPTH - 1; lvl >= 0; --lvl) {
        int R = NB << lvl;
        dim3 grid(R / 64, 4);
        float* c_o        = (lvl & 1) ? cb1 : cb0;
        const float* c_ch = ((lvl + 1) & 1) ? cb1 : cb0;
        const unsigned short* hA_this = (lvl & 1) ? hA1 : hA0;
        unsigned short* hA_par = (lvl > 0) ? (((lvl - 1) & 1) ? hA1 : hA0) : nullptr;

        if (lvl == DEPTH - 1) {
            level_gemm<true><<<grid, 256, 0, stream>>>(
                xb, nullptr, Wcat, nullptr, b_i, b_o, b_u, b_f,
                c_o, hA_par, h_all, lvl);
        } else {
            level_gemm<false><<<grid, 256, 0, stream>>>(
                xb, hA_this, Wcat, c_ch, b_i, b_o, b_u, b_f,
                c_o, hA_par, h_all, lvl);
        }
    }

    softmax_kernel<<<8188, 256, 0, stream>>>(h_all, W_s, b_s, out);
}

// Round 3
// 1397.359 us; speedup vs baseline: 12.5223x; 1.4774x over previous
//
#include <hip/hip_runtime.h>
#include <math.h>

#define HID 256
#define NCLASS 5
#define DEPTH 11
#define NB 128
#define NN 2047

typedef __attribute__((ext_vector_type(8))) short bf16x8_t;
typedef __attribute__((ext_vector_type(4))) float f32x4_t;

__device__ __forceinline__ float bf2f(unsigned short u) {
    return __uint_as_float(((unsigned)u) << 16);
}
__device__ __forceinline__ unsigned short f2bf(float f) {
    unsigned x = __float_as_uint(f);
    unsigned r = (x + 0x7fff + ((x >> 16) & 1)) >> 16;   // RNE
    return (unsigned short)r;
}
__device__ __forceinline__ float sigmoidf_(float x) {
    return 1.0f / (1.0f + __expf(-x));
}
// async global->LDS, 16B per lane; LDS dest = wave-uniform base + lane*16
__device__ __forceinline__ void gl_lds16(const void* g, void* l) {
    __builtin_amdgcn_global_load_lds(
        (const __attribute__((address_space(1))) unsigned int*)g,
        (__attribute__((address_space(3))) unsigned int*)l,
        16, 0, 0);
}

// ---------------- Wcat: (1280 n, 768 k) bf16, gate-major: n = g*256 + ch ----------------
// gate g: 0=i,1=o,2=u,3=f0,4=f1 ; k: [0,256)=W_g, [256,512)=U left, [512,768)=U right
__global__ __launch_bounds__(256)
void prep_wcat(const float* __restrict__ W_i, const float* __restrict__ U_i,
               const float* __restrict__ W_f, const float* __restrict__ U_f,
               const float* __restrict__ W_o, const float* __restrict__ U_o,
               const float* __restrict__ W_u, const float* __restrict__ U_u,
               unsigned short* __restrict__ Wcat)
{
    int idx = blockIdx.x * 256 + threadIdx.x;     // 0 .. 1280*768-1
    int k = idx % 768;
    int n = idx / 768;
    int g = n >> 8;
    int ch = n & 255;
    int seg = k >> 8;
    int kk = k & 255;
    float v;
    if (seg == 0) {
        const float* W = (g == 0) ? W_i : (g == 1) ? W_o : (g == 2) ? W_u : W_f;
        v = W[ch * 256 + kk];
    } else {
        int side = seg - 1;
        if (g == 0)      v = U_i[(side * 256 + ch) * 256 + kk];
        else if (g == 1) v = U_o[(side * 256 + ch) * 256 + kk];
        else if (g == 2) v = U_u[(side * 256 + ch) * 256 + kk];
        else             v = U_f[(((g - 3) * 2 + side) * 256 + ch) * 256 + kk];
    }
    Wcat[(size_t)n * 768 + k] = f2bf(v);
}

// ---------------- x cast fp32 -> bf16 ----------------
__global__ __launch_bounds__(256)
void cast_x_kernel(const float* __restrict__ x, unsigned short* __restrict__ xb)
{
    size_t i = ((size_t)blockIdx.x * 256 + threadIdx.x) * 8;
    float4 a = *(const float4*)(x + i);
    float4 b = *(const float4*)(x + i + 4);
    unsigned short o[8] = {f2bf(a.x), f2bf(a.y), f2bf(a.z), f2bf(a.w),
                           f2bf(b.x), f2bf(b.y), f2bf(b.z), f2bf(b.w)};
    *(uint4*)(xb + i) = *(uint4*)o;
}

// ---------------- fused level GEMM + LSTM epilogue (m97-style) ----------------
// Block: 512 thr = 8 waves, tile 128 rows x NT*16 cols, BK=32 (=MFMA K).
// Wave (rh = w&1, cq = w>>2? no: cq = w>>1): 64 rows x NG*16 cols, n-tiles t = j*4+cq.
// LDS granule order == MFMA fragment-read order: tile base + lane*16 holds
// (row/n = lane&15, kq = lane>>4)  -> conflict-free ds_read_b128 AND valid
// global_load_lds dest (contiguous 1KB per wave-instruction).
template<int NG, int NK, bool LEAF>
__global__ __launch_bounds__(512, 4)
void level_gemm(const unsigned short* __restrict__ xb,
                const unsigned short* __restrict__ hA,       // (rows,512) [hL|hR]; null if LEAF
                const unsigned short* __restrict__ Wcat,
                const float* __restrict__ c_child,           // (child rows,256); null if LEAF
                const float* __restrict__ b_i, const float* __restrict__ b_o,
                const float* __restrict__ b_u, const float* __restrict__ b_f,
                float* __restrict__ c_out,                   // (rows,256)
                unsigned short* __restrict__ hA_parent,      // (rows/2,512) or null
                unsigned short* __restrict__ h_all,          // (B,NN,256) bf16
                int lgM)
{
    constexpr int NT = NG * 4;            // n-tiles per block (20 or 12)
    constexpr int BOFF = 8192;            // A region: 8 m-tiles * 1KB
    __shared__ __align__(16) char smem[BOFF + NT * 1024];

    const int tid  = threadIdx.x;
    const int w    = tid >> 6, lane = tid & 63;
    const int quad = lane >> 4, p = lane & 15;
    const int rh = w & 1, cq = w >> 1;
    const int chblk = blockIdx.x;
    const int R0 = blockIdx.y * 128;
    const int M = 1 << lgM, s = M - 1;

    // ---- per-lane staging source bases (fixed across K-steps) ----
    // A: wave w stages m-tile w; lane covers (row = R0 + w*16 + p, k-sub = quad*8)
    const int arow = R0 + w * 16 + p;
    const int ab = arow >> lgM, am = arow & (M - 1);
    const unsigned short* a_x = xb + ((size_t)ab * NN + s + am) * 256 + quad * 8;
    const unsigned short* a_h = LEAF ? (const unsigned short*)nullptr
                                     : hA + (size_t)arow * 512 + quad * 8;
    // B: wave w stages n-tiles [t0, t0+nbt)
    const int nbt = LEAF ? (w < 4 ? 2 : 1) : (w < 4 ? 3 : 2);
    const int t0  = LEAF ? (w < 4 ? w * 2 : 8 + (w - 4))
                         : (w < 4 ? w * 3 : 12 + (w - 4) * 2);
    const unsigned short* bsrc[3];
    #pragma unroll
    for (int j = 0; j < 3; ++j) {
        int t = t0 + ((j < nbt) ? j : 0);
        int n = (t >> 2) * 256 + chblk * 64 + (t & 3) * 16 + p;
        bsrc[j] = Wcat + (size_t)n * 768 + quad * 8;
    }

    f32x4_t acc[4][NG];
    #pragma unroll
    for (int mi = 0; mi < 4; ++mi)
        #pragma unroll
        for (int j = 0; j < NG; ++j)
            acc[mi][j] = (f32x4_t){0.f, 0.f, 0.f, 0.f};

    for (int step = 0; step < NK; ++step) {
        const int k0 = step * 32;
        __syncthreads();
        // stage A (1 instr/wave) + B (2-3 instrs/wave), async direct to LDS
        const unsigned short* asrc = (LEAF || k0 < 256) ? (a_x + k0) : (a_h + (k0 - 256));
        gl_lds16(asrc, smem + w * 1024);
        #pragma unroll
        for (int j = 0; j < 3; ++j)
            if (j < nbt) gl_lds16(bsrc[j] + k0, smem + BOFF + (t0 + j) * 1024);
        __syncthreads();   // compiler emits vmcnt(0) drain before s_barrier

        // compute: 4 m-frags, NG n-frags, 4*NG MFMAs
        bf16x8_t af[4];
        #pragma unroll
        for (int mi = 0; mi < 4; ++mi)
            af[mi] = *(const bf16x8_t*)(smem + ((rh * 4 + mi) * 64 + lane) * 16);
        #pragma unroll
        for (int j = 0; j < NG; ++j) {
            bf16x8_t bfr = *(const bf16x8_t*)(smem + BOFF + ((j * 4 + cq) * 64 + lane) * 16);
            #pragma unroll
            for (int mi = 0; mi < 4; ++mi)
                acc[mi][j] = __builtin_amdgcn_mfma_f32_16x16x32_bf16(af[mi], bfr, acc[mi][j], 0, 0, 0);
        }
    }

    // ---- fused epilogue: each lane owns all NG gates for (16 rows x 1 channel) ----
    const int gch = chblk * 64 + cq * 16 + p;
    const float bi = b_i[gch], bo = b_o[gch], bu = b_u[gch];
    const float bfv = LEAF ? 0.f : b_f[gch];

    #pragma unroll
    for (int mi = 0; mi < 4; ++mi) {
        const int rowq = R0 + rh * 64 + mi * 16 + quad * 4;
        #pragma unroll
        for (int reg = 0; reg < 4; ++reg) {
            const int grow = rowq + reg;
            const int b = grow >> lgM, m = grow & (M - 1);
            float ig = sigmoidf_(acc[mi][0][reg] + bi);
            float og = sigmoidf_(acc[mi][1][reg] + bo);
            float ug = tanhf(acc[mi][2][reg] + bu);
            float c;
            if (LEAF) {
                c = ig * ug;
            } else {
                const float* crow = c_child + ((size_t)b * (M << 1) + 2 * m) * 256 + gch;
                float f0 = sigmoidf_(acc[mi][3][reg] + bfv);
                float f1 = sigmoidf_(acc[mi][4][reg] + bfv);
                c = fmaf(f0, crow[0], fmaf(f1, crow[256], ig * ug));
            }
            float h = og * tanhf(c);
            c_out[(size_t)grow * 256 + gch] = c;
            unsigned short hb = f2bf(h);
            h_all[((size_t)b * NN + s + m) * 256 + gch] = hb;
            if (hA_parent)
                hA_parent[((size_t)b * (M >> 1) + (m >> 1)) * 512 + (m & 1) * 256 + gch] = hb;
        }
    }
}

// ---------------- classifier softmax over all nodes ----------------
__global__ __launch_bounds__(256)
void softmax_kernel(const unsigned short* __restrict__ h_all,
                    const float* __restrict__ W_s, const float* __restrict__ b_s,
                    float* __restrict__ out)
{
    __shared__ float Ws[5 * 256];
    int tid = threadIdx.x;
    for (int i = tid; i < 1280; i += 256) Ws[i] = W_s[i];
    __syncthreads();

    int r = tid >> 3, q = tid & 7;
    size_t row = (size_t)blockIdx.x * 32 + r;
    const unsigned short* hp = h_all + row * 256 + q * 32;

    float p0 = 0.f, p1 = 0.f, p2 = 0.f, p3 = 0.f, p4 = 0.f;
    #pragma unroll
    for (int kk = 0; kk < 32; kk += 8) {
        uint4 raw = *(const uint4*)(hp + kk);
        unsigned short hu[8];
        *(uint4*)hu = raw;
        #pragma unroll
        for (int e = 0; e < 8; ++e) {
            float hvv = bf2f(hu[e]);
            int k = q * 32 + kk + e;
            p0 = fmaf(Ws[k],        hvv, p0);
            p1 = fmaf(Ws[256 + k],  hvv, p1);
            p2 = fmaf(Ws[512 + k],  hvv, p2);
            p3 = fmaf(Ws[768 + k],  hvv, p3);
            p4 = fmaf(Ws[1024 + k], hvv, p4);
        }
    }
    #pragma unroll
    for (int off = 4; off; off >>= 1) {
        p0 += __shfl_down(p0, off, 8);
        p1 += __shfl_down(p1, off, 8);
        p2 += __shfl_down(p2, off, 8);
        p3 += __shfl_down(p3, off, 8);
        p4 += __shfl_down(p4, off, 8);
    }
    if (q == 0) {
        float l0 = p0 + b_s[0], l1 = p1 + b_s[1], l2 = p2 + b_s[2];
        float l3 = p3 + b_s[3], l4 = p4 + b_s[4];
        float mx = fmaxf(fmaxf(fmaxf(l0, l1), fmaxf(l2, l3)), l4);
        float e0 = __expf(l0 - mx), e1 = __expf(l1 - mx), e2 = __expf(l2 - mx);
        float e3 = __expf(l3 - mx), e4 = __expf(l4 - mx);
        float inv = 1.0f / (e0 + e1 + e2 + e3 + e4);
        float* orow = out + row * NCLASS;
        orow[0] = e0 * inv;
        orow[1] = e1 * inv;
        orow[2] = e2 * inv;
        orow[3] = e3 * inv;
        orow[4] = e4 * inv;
    }
}

extern "C" void kernel_launch(void* const* d_in, const int* in_sizes, int n_in,
                              void* d_out, int out_size, void* d_ws, size_t ws_size,
                              hipStream_t stream) {
    const float* x   = (const float*)d_in[0];
    const float* W_i = (const float*)d_in[1];
    const float* U_i = (const float*)d_in[2];
    const float* b_i = (const float*)d_in[3];
    const float* W_f = (const float*)d_in[4];
    const float* U_f = (const float*)d_in[5];
    const float* b_f = (const float*)d_in[6];
    const float* W_o = (const float*)d_in[7];
    const float* U_o = (const float*)d_in[8];
    const float* b_o = (const float*)d_in[9];
    const float* W_u = (const float*)d_in[10];
    const float* U_u = (const float*)d_in[11];
    const float* b_u = (const float*)d_in[12];
    const float* W_s = (const float*)d_in[13];
    const float* b_s = (const float*)d_in[14];
    float* out = (float*)d_out;

    char* p = (char*)d_ws;
    unsigned short* Wcat  = (unsigned short*)p; p += 2097152;       // 1280*768*2
    unsigned short* xb    = (unsigned short*)p; p += 134152192;     // 128*2047*256*2
    unsigned short* h_all = (unsigned short*)p; p += 134152192;
    unsigned short* hA0   = (unsigned short*)p; p += 33554432;      // even-level hA input
    unsigned short* hA1   = (unsigned short*)p; p += 67108864;      // odd-level hA input
    float* cb0 = (float*)p; p += 134217728;                         // even-level c
    float* cb1 = (float*)p; p += 67108864;                          // odd-level c

    prep_wcat<<<3840, 256, 0, stream>>>(W_i, U_i, W_f, U_f, W_o, U_o, W_u, U_u, Wcat);
    cast_x_kernel<<<32752, 256, 0, stream>>>(x, xb);

    for (int lvl = DEPTH - 1; lvl >= 0; --lvl) {
        dim3 grid(4, 1 << lvl);             // x = chblk (A-reuse adjacency), y = rowblock
        float* c_o        = (lvl & 1) ? cb1 : cb0;
        const float* c_ch = ((lvl + 1) & 1) ? cb1 : cb0;
        const unsigned short* hA_this = (lvl & 1) ? hA1 : hA0;
        unsigned short* hA_par = (lvl > 0) ? (((lvl - 1) & 1) ? hA1 : hA0) : nullptr;

        if (lvl == DEPTH - 1) {
            level_gemm<3, 8, true><<<grid, 512, 0, stream>>>(
                xb, nullptr, Wcat, nullptr, b_i, b_o, b_u, b_f,
                c_o, hA_par, h_all, lvl);
        } else {
            level_gemm<5, 24, false><<<grid, 512, 0, stream>>>(
                xb, hA_this, Wcat, c_ch, b_i, b_o, b_u, b_f,
                c_o, hA_par, h_all, lvl);
        }
    }

    softmax_kernel<<<8188, 256, 0, stream>>>(h_all, W_s, b_s, out);
}